// Round 12
// baseline (254.671 us; speedup 1.0000x reference)
//
#include <hip/hip_runtime.h>
#include <math.h>

// TIME_WARPING: not-a-knot cubic spline fit + warped resample, fused.
//
// Math: spline A M = rhs with M1 = y0-2y1+y2 (exact), MS2 = y[S-3]-2y[S-2]+y[S-1]
//   (exact), M0 = 2M1-M2, M[S-1] = 2MS2-M[S-3]; interior Toeplitz(1,4,1) inverse
//   = conv with G(k) = (-1)^k r^k/(2 sqrt3), r = 2-sqrt(3). Interior M == conv of
//   y with H = 6*(G (*) [1,-2,1]) truncated at WC=6 (R7/R8/R11-validated: absmax
//   0.015625 == W=8). Edge region: exact f-based conv (W=8) + image corrections.
//
// R12: TWO ADJACENT SIGNALS PER BLOCK, phase-pipelined (last untested axis).
//  Post-mortem R0-R11: LDS size, conflicts, barriers, VALU, persistence, and
//  occupancy (25->69%, R11) ALL falsified -- kernel pinned 80-84us, no pipe
//  >31%. Remaining hypothesis: per-block serial phase chain (stage->drain->
//  conv->drain->gather->store-drain) with only 2-deep cross-block overlap.
//  * Block handles signals 2*bid, 2*bid+1 (same b -> same mask/scale; memory
//    contiguous -> NO traffic change, unlike R4's far-apart persistence).
//  * Signal-B global load issued BEFORE conv-A: ~900cy HBM latency hides under
//    conv-A. B's ds_write after gather-A (value long landed). Plain
//    __syncthreads everywhere (no custom barrier semantics).
//  * Halves block launch/drain count; hides half the stage latencies.
//  * LDS: syA+syB+sm = 48KB -> 2 blocks/CU x 16 waves (occupancy as R11).
//  Pre-commit: if still 80-84us/dispatch, declare plateau structural.

#define SLEN 4096
#define WRAD 8   // edge-path truncation (exact harness-verified path)
#define WC   6   // interior truncation (R7/R8/R11-validated)
#define BLK  1024

typedef float f32x4 __attribute__((ext_vector_type(4)));

// ---- pass C: M = conv(y) for this thread's 4-wide group ----
__device__ __forceinline__ void spline_conv(const float* __restrict__ sy,
                                            float* __restrict__ sm, int t)
{
    // Green taps (compile-time folded)
    const float r = 0.26794919243112270f;  // 2 - sqrt(3)
    float G[WRAD + 1];
    G[0] = 0.28867513459481287f;           // 1 / (2 sqrt(3))
    #pragma unroll
    for (int k = 1; k <= WRAD; ++k) G[k] = -G[k - 1] * r;
    float Hh[WC + 2];
    Hh[0] = 12.0f * (G[1] - G[0]);
    #pragma unroll
    for (int k = 1; k < WC; ++k) Hh[k] = 6.0f * (G[k - 1] - 2.0f * G[k] + G[k + 1]);
    Hh[WC]     = 6.0f * (G[WC - 1] - 2.0f * G[WC]);   // G[WC+1] treated as 0
    Hh[WC + 1] = 6.0f * G[WC];
    const float log2r = -1.8999686269529532f;  // log2(2 - sqrt(3))

    const int j0 = 4 * t;
    if (j0 >= 36 && j0 <= SLEN - 44) {
        // interior: window y[j0-8 .. j0+11], 5 aligned b128 reads,
        // lane stride 16B (proven conflict-free pattern).
        float wv[20];
        #pragma unroll
        for (int m = 0; m < 5; ++m)
            *(float4*)&wv[4 * m] = *(const float4*)&sy[j0 - 8 + 4 * m];
        float mv[4];
        #pragma unroll
        for (int e = 0; e < 4; ++e) {      // y[j0+e] = wv[8+e]
            float acc = Hh[0] * wv[8 + e];
            #pragma unroll
            for (int k = 1; k <= WC + 1; ++k)
                acc += Hh[k] * (wv[8 + e - k] + wv[8 + e + k]);
            mv[e] = acc;
        }
        *(float4*)&sm[j0] = make_float4(mv[0], mv[1], mv[2], mv[3]);
    } else {
        // edge path (~19 lanes, waves 0 and 15): exact f-based conv (W=8)
        // + image corrections, verbatim harness-verified math.
        const float M1  = sy[0]        - 2.0f * sy[1]        + sy[2];
        const float MS2 = sy[SLEN - 3] - 2.0f * sy[SLEN - 2] + sy[SLEN - 1];

        float v1 = 0.0f, vS2 = 0.0f;
        #pragma unroll
        for (int k = 1; k <= WRAD; ++k) {
            const int ja = 1 + k;                        // 2..9
            float fa = 6.0f * (sy[ja - 1] - 2.0f * sy[ja] + sy[ja + 1]);
            if (ja == 2) fa -= M1;
            v1 += G[k] * fa;
            const int jb = SLEN - 2 - k;                 // S-3 .. S-10
            float fb = 6.0f * (sy[jb - 1] - 2.0f * sy[jb] + sy[jb + 1]);
            if (jb == SLEN - 3) fb -= MS2;
            vS2 += G[k] * fb;
        }

        float wv[28];                  // y[j0-12 .. j0+15], guarded quads
        #pragma unroll
        for (int m = 0; m < 7; ++m) {
            const int q = j0 - 12 + 4 * m;
            float4 v = make_float4(0.0f, 0.0f, 0.0f, 0.0f);
            if (q >= 0 && q <= SLEN - 4) v = *(const float4*)&sy[q];
            *(float4*)&wv[4 * m] = v;
        }
        float fw[20];                  // f[j0-8 .. j0+11]
        #pragma unroll
        for (int p = 0; p < 20; ++p) {
            const int jj = j0 + p - 8;
            float fv = 6.0f * (wv[p + 3] - 2.0f * wv[p + 4] + wv[p + 5]);
            if (jj < 2 || jj > SLEN - 3) fv = 0.0f;
            if (jj == 2)        fv -= M1;
            if (jj == SLEN - 3) fv -= MS2;
            fw[p] = fv;
        }
        float mv[4];
        #pragma unroll
        for (int e = 0; e < 4; ++e) {
            float acc = G[0] * fw[8 + e];
            #pragma unroll
            for (int k = 1; k <= WRAD; ++k)
                acc += G[k] * (fw[8 + e - k] + fw[8 + e + k]);
            const int i = j0 + e;
            if (i >= 2 && i <= 34) {
                float cc = v1 * exp2f((float)(i - 1) * log2r);
                acc += (i & 1) ? -cc : cc;
            }
            if (i >= SLEN - 36 && i <= SLEN - 3) {
                float cc = vS2 * exp2f((float)(SLEN - 2 - i) * log2r);
                acc += (i & 1) ? cc : -cc;
            }
            mv[e] = acc;
        }
        if (j0 == 0)        { mv[1] = M1;  mv[0] = 2.0f * M1  - mv[2]; }
        if (j0 == SLEN - 4) { mv[2] = MS2; mv[3] = 2.0f * MS2 - mv[1]; }
        *(float4*)&sm[j0] = make_float4(mv[0], mv[1], mv[2], mv[3]);
    }
}

// ---- pass D: warped evaluation, 4 outputs/thread, j = t + 1024*q ----
__device__ __forceinline__ void spline_eval(const float* __restrict__ sy,
                                            const float* __restrict__ sm,
                                            float* __restrict__ o,
                                            float sc, int t)
{
    #pragma unroll
    for (int q = 0; q < 4; ++q) {
        const int j = t + BLK * q;
        float w = fminf((float)j * sc, (float)(SLEN - 1));
        int idx = (int)w;
        if (idx > SLEN - 2) idx = SLEN - 2;
        const float tt = w - (float)idx;
        const float y0 = sy[idx];
        const float y1 = sy[idx + 1];
        const float m0 = sm[idx];
        const float m1 = sm[idx + 1];
        const float bb = (y1 - y0) - (2.0f * m0 + m1) * (1.0f / 6.0f);
        const float cc = 0.5f * m0;
        const float dd = (m1 - m0) * (1.0f / 6.0f);
        const float res = y0 + tt * (bb + tt * (cc + tt * dd));
        __builtin_nontemporal_store(res, &o[j]);
    }
}

__global__ __launch_bounds__(BLK, 8) void time_warp_kernel(
    const float* __restrict__ x,
    const float* __restrict__ scale,
    const int*   __restrict__ apply_mask,
    float* __restrict__ out,
    int C)
{
    __shared__ float syA[SLEN];    // signal A               16384 B
    __shared__ float syB[SLEN];    // signal B               16384 B
    __shared__ float sm [SLEN];    // M (reused A then B)    16384 B  => 48 KB

    const int pid = blockIdx.x;    // pair id: signals 2*pid, 2*pid+1
    const int s0  = 2 * pid;
    const int b   = s0 / C;        // C=64 even => both signals share b
    const int t   = threadIdx.x;
    const float* __restrict__ xA = x   + (size_t)s0 * SLEN;
    const float* __restrict__ xB = xA + SLEN;
    float*       __restrict__ oA = out + (size_t)s0 * SLEN;
    float*       __restrict__ oB = oA + SLEN;

    // per-sample apply decision (block-uniform, before any barrier)
    if (apply_mask[b] == 0) {
        f32x4 vA = ((const f32x4*)xA)[t];
        f32x4 vB = ((const f32x4*)xB)[t];
        __builtin_nontemporal_store(vA, &((f32x4*)oA)[t]);
        __builtin_nontemporal_store(vB, &((f32x4*)oB)[t]);
        return;
    }

    const float sc = scale[b];

    // stage A: one float4/thread, 16B lane stride
    *(float4*)&syA[4 * t] = ((const float4*)xA)[t];
    __syncthreads();                         // bar1: syA visible

    // prefetch B NOW -- its ~900cy HBM latency hides under conv A
    const float4 b4 = ((const float4*)xB)[t];

    spline_conv(syA, sm, t);                 // conv A -> sm
    __syncthreads();                         // bar2: sm visible (b4 landed too)

    spline_eval(syA, sm, oA, sc, t);         // gather A + NT store A
    *(float4*)&syB[4 * t] = b4;              // stage B (no wait: b4 in regs)
    __syncthreads();                         // bar3: gather-A done, syB visible

    spline_conv(syB, sm, t);                 // conv B -> sm (safe: bar3)
    __syncthreads();                         // bar4: sm visible

    spline_eval(syB, sm, oB, sc, t);         // gather B + NT store B
}

extern "C" void kernel_launch(void* const* d_in, const int* in_sizes, int n_in,
                              void* d_out, int out_size, void* d_ws, size_t ws_size,
                              hipStream_t stream) {
    const float* x     = (const float*)d_in[0];
    const float* scale = (const float*)d_in[1];
    const int*   mask  = (const int*)d_in[2];
    float*       out   = (float*)d_out;

    const int B     = in_sizes[1];            // 128
    const int total = in_sizes[0];            // B*C*S
    const int C     = total / (B * SLEN);     // 64
    const int nsig  = B * C;                  // 8192
    const int nblk  = nsig / 2;               // 4096 pair-blocks

    time_warp_kernel<<<nblk, BLK, 0, stream>>>(x, scale, mask, out, C);
}